// Round 25
// baseline (52.309 us; speedup 1.0000x reference)
//
#include <hip/hip_runtime.h>
#include <math.h>

#define BT    8192
#define TSEQ  2048
#define DIN   1024
#define DK    64

typedef __attribute__((ext_vector_type(8))) short bf16x8;
typedef __attribute__((ext_vector_type(4))) short bf16x4;
typedef __attribute__((ext_vector_type(4))) float f32x4;

static __device__ inline unsigned short f2bf(float f) {
    union { float f; unsigned u; } v; v.f = f;
    unsigned r = v.u + 0x7fff + ((v.u >> 16) & 1);   // RNE
    return (unsigned short)(r >> 16);
}

static __device__ inline bf16x4 cvt4(float4 a) {
    bf16x4 r;
    r[0] = (short)f2bf(a.x); r[1] = (short)f2bf(a.y);
    r[2] = (short)f2bf(a.z); r[3] = (short)f2bf(a.w);
    return r;
}

// ---------------- WT[mat*64+n][k] = bf16(W[k][n]) : [192][1024] -------------
__global__ __launch_bounds__(256) void wt_kernel(
    const float* __restrict__ Wq, const float* __restrict__ Wk,
    const float* __restrict__ Wv, unsigned short* __restrict__ WT)
{
    __shared__ float ws[64][65];
    const int tid = threadIdx.x;
    const int mat = blockIdx.x >> 4;               // 0..2
    const int k0  = (blockIdx.x & 15) << 6;        // 0..960
    const float* W = (mat == 0) ? Wq : ((mat == 1) ? Wk : Wv);

    const int j = tid & 63;
    for (int i = tid >> 6; i < 64; i += 4)
        ws[i][j] = W[(size_t)(k0 + i) * DK + j];
    __syncthreads();

    const int n  = tid & 63;
    const int c0 = (tid >> 6) << 4;
    unsigned short* dst = WT + (size_t)(mat * 64 + n) * DIN + k0 + c0;
    #pragma unroll
    for (int c = 0; c < 16; ++c) dst[c] = f2bf(ws[c0 + c][n]);
}

// ---------------- MFMA projection: barrier-free per-wave WT pipeline (R18) --
__global__ __launch_bounds__(256, 2) void proj_kernel(
    const float* __restrict__ x, const unsigned short* __restrict__ WT,
    unsigned short* __restrict__ Qb, unsigned short* __restrict__ Kb,
    unsigned short* __restrict__ VT)
{
    __shared__ unsigned short xs[16][1032];        // 33.0 KB
    __shared__ unsigned short wtb[192][72];        // 27.6 KB, 48 rows/wave
    const int tid = threadIdx.x;
    const int m0 = blockIdx.x * 16;

    {
        const int r = tid >> 4;
        const int c = (tid & 15) << 2;
        const float* src = x + (size_t)(m0 + r) * DIN + c;
        float4 tmp[16];
        #pragma unroll
        for (int s = 0; s < 16; ++s) tmp[s] = *(const float4*)(src + s * 64);
        #pragma unroll
        for (int s = 0; s < 16; ++s) *(bf16x4*)&xs[r][c + s * 64] = cvt4(tmp[s]);
    }

    const int lane = tid & 63;
    const int w    = tid >> 6;                    // 0..3 (colgroup, 48 cols)
    const int lr = lane & 15, lg = lane >> 4;

    f32x4 acc[3];
    #pragma unroll
    for (int nt = 0; nt < 3; ++nt) acc[nt] = (f32x4){0.f, 0.f, 0.f, 0.f};

    const unsigned short* wt_w = WT + (size_t)w * 48 * DIN;   // wave's rows
    bf16x8 cur[6], nxt[6];
    #pragma unroll
    for (int i = 0; i < 6; ++i) {                 // prologue: chunk 0 loads
        const int c = lane + i * 64;              // 0..383
        const int nl = c >> 3;                    // local row 0..47
        const int sl = c & 7;                     // 16B slot
        cur[i] = *(const bf16x8*)(wt_w + (size_t)nl * DIN + (sl << 3));
    }

    __syncthreads();                              // xs ready (only barrier)

    for (int kc = 0; kc < 16; ++kc) {
        const int k0 = kc << 6;

        if (kc + 1 < 16) {
            #pragma unroll
            for (int i = 0; i < 6; ++i) {
                const int c = lane + i * 64;
                const int nl = c >> 3;
                const int sl = c & 7;
                nxt[i] = *(const bf16x8*)(wt_w + (size_t)nl * DIN
                                          + (k0 + 64) + (sl << 3));
            }
        }

        #pragma unroll
        for (int i = 0; i < 6; ++i) {
            const int c = lane + i * 64;
            const int n = w * 48 + (c >> 3);
            const int sl = c & 7;
            *(bf16x8*)&wtb[n][((sl + n) & 7) << 3] = cur[i];
        }
        asm volatile("s_waitcnt lgkmcnt(0)" ::: "memory");  // wave-local W->R

        #pragma unroll
        for (int st = 0; st < 2; ++st) {
            const bf16x8 af = *(const bf16x8*)&xs[lr][k0 + (st << 5) + (lg << 3)];
            #pragma unroll
            for (int nt = 0; nt < 3; ++nt) {
                const int n = w * 48 + nt * 16 + lr;
                const int sl = (st << 2) + lg;
                const bf16x8 bf = *(const bf16x8*)&wtb[n][((sl + n) & 7) << 3];
                acc[nt] = __builtin_amdgcn_mfma_f32_16x16x32_bf16(af, bf, acc[nt], 0, 0, 0);
            }
        }

        if (kc + 1 < 16) {
            #pragma unroll
            for (int i = 0; i < 6; ++i) cur[i] = nxt[i];
        }
    }

    const float qsc = 0.125f * 1.44269504088896340736f;  // scale * log2(e)
    #pragma unroll
    for (int nt = 0; nt < 3; ++nt) {
        const int gct = w * 3 + nt;                      // global 16-col tile
        if (gct < 8) {
            #pragma unroll
            for (int r = 0; r < 4; ++r) {
                const int row = m0 + (lg << 2) + r;
                const float vv = acc[nt][r];
                if (gct < 4) Qb[(size_t)row * DK + gct * 16 + lr] = f2bf(vv * qsc);
                else         Kb[(size_t)row * DK + (gct - 4) * 16 + lr] = f2bf(vv);
            }
        } else {
            // VT blocked: tile = (batch*32 + t/64), row d, col t%64; 8B store
            const int d = (gct - 8) * 16 + lr;
            const int t = m0 + (lg << 2);
            const int tb = t & (TSEQ - 1);
            const size_t tile = (size_t)(t >> 11) * 32 + (tb >> 6);
            ushort4 pk;
            pk.x = f2bf(acc[nt][0]); pk.y = f2bf(acc[nt][1]);
            pk.z = f2bf(acc[nt][2]); pk.w = f2bf(acc[nt][3]);
            *(ushort4*)&VT[(tile * DK + d) * 64 + (tb & 63)] = pk;
        }
    }
}

// ---------------- MFMA flash attention: block-staged K/V (VMEM-instr cut) ---
// Invariant from R20-R24: attn time ~ per-CU VMEM instr count x ~80cy.
// Per-wave fragment loads = 1 KB/instr (hard cap). Block-cooperative staging
// = 4 KB/instr. 256 blocks (1/CU) x 4 waves; block = 32 Q-rows (2 tiles);
// per 128-key chunk: stage K (16 KB) + blocked-V (16 KB) with 8 coalesced
// instrs into double-buffered XOR-swizzled LDS; wave (tile t, half h)
// computes keys 64h..64h+63 from LDS. Worst CU: 16*8 = 128 VMEM instrs
// (vs 528 in R21). One barrier per chunk; stage-next issued before compute.
__global__ __launch_bounds__(256, 1) void attn_kernel(
    const unsigned short* __restrict__ Qb, const unsigned short* __restrict__ Kb,
    const unsigned short* __restrict__ VT, float* __restrict__ O)
{
    union __align__(16) Sh {
        struct { unsigned short K[2][128][64]; unsigned short V[2][2][64][64]; } kv; // 64 KB
        struct { float Op[4][16][68]; float mp[4][16]; float Lp[4][16]; } mg;        // 17.9 KB
    };
    __shared__ Sh sh;
    __shared__ __align__(16) unsigned short P_lds[4][16][72];

    const int tid  = threadIdx.x;
    const int lane = tid & 63;
    const int w    = tid >> 6;            // 0..3
    const int t    = w >> 1;              // Q-tile 0/1
    const int h    = w & 1;               // key-half parity
    const int bi   = blockIdx.x;          // 0..255
    const int batch = bi & 3;
    const int jj   = bi >> 2;             // 0..63
    const int t0   = jj << 5;             // block's first row (within batch)
    const int t_first = t0 + (t << 4);
    const int t_last  = t_first + 15;
    const int q0t  = (batch << 11) + t_first;
    const int lr = lane & 15, lg = lane >> 4;

    const unsigned short* Qrow = Qb + (size_t)(q0t + lr) * DK + (lg << 3);
    const bf16x8 qf0 = *(const bf16x8*)(Qrow);
    const bf16x8 qf1 = *(const bf16x8*)(Qrow + 32);

    const unsigned short* Kbase = Kb + (size_t)batch * TSEQ * DK;
    const unsigned short* Vbase = VT + (size_t)batch * 32 * DK * 64;

    f32x4 oacc[4];
    #pragma unroll
    for (int dt = 0; dt < 4; ++dt) oacc[dt] = (f32x4){0.f, 0.f, 0.f, 0.f};
    float m[4] = {-INFINITY, -INFINITY, -INFINITY, -INFINITY};
    float L[4] = {0.f, 0.f, 0.f, 0.f};

    const int nkb2 = ((t0 + 31) >> 7) + 1;    // 128-key chunks (max 16)

// stage chunk C2 into regs (8 coalesced 4-KB loads block-wide)
#define STAGE_LOAD(C2) do {                                                   \
    const unsigned short* ksrc_ = Kbase + ((size_t)(C2) << 13);               \
    const unsigned short* vsrc_ = Vbase + ((size_t)(C2) << 13);               \
    _Pragma("unroll")                                                         \
    for (int ld_ = 0; ld_ < 4; ++ld_) {                                       \
        kst[ld_] = *(const bf16x8*)(ksrc_ + (((ld_ << 8) + tid) << 3));       \
        vst[ld_] = *(const bf16x8*)(vsrc_ + (((ld_ << 8) + tid) << 3));       \
    }                                                                         \
} while (0)

// write staged regs into swizzled LDS buffer B
#define STAGE_WRITE(B) do {                                                   \
    _Pragma("unroll")                                                         \
    for (int ld_ = 0; ld_ < 4; ++ld_) {                                       \
        const int c_ = (ld_ << 8) + tid;            /* 0..1023 */             \
        const int rk_ = c_ >> 3, slk_ = c_ & 7;                               \
        *(bf16x8*)&sh.kv.K[B][rk_][((slk_ ^ (rk_ & 7)) << 3)] = kst[ld_];     \
        const int jv_ = c_ >> 9, cc_ = c_ & 511;                              \
        const int rv_ = cc_ >> 3, slv_ = cc_ & 7;                             \
        *(bf16x8*)&sh.kv.V[B][jv_][rv_][((slv_ ^ (rv_ & 7)) << 3)] = vst[ld_];\
    }                                                                         \
} while (0)

    bf16x8 kst[4], vst[4];
    STAGE_LOAD(0);
    STAGE_WRITE(0);
    __syncthreads();

    for (int i2 = 0; i2 < nkb2; ++i2) {
        const int curb = i2 & 1;

        if (i2 + 1 < nkb2) STAGE_LOAD(i2 + 1);    // issue early (T14)

        const int s0 = (i2 << 7) + (h << 6);
        if (s0 <= t_last) {
            // ---- QK^T from swizzled K LDS ----
            f32x4 s[4];
            #pragma unroll
            for (int ct = 0; ct < 4; ++ct) {
                const int row = (h << 6) + ct * 16 + lr;
                const bf16x8 k0 = *(const bf16x8*)&sh.kv.K[curb][row][((lg ^ (row & 7)) << 3)];
                const bf16x8 k1 = *(const bf16x8*)&sh.kv.K[curb][row][(((lg + 4) ^ (row & 7)) << 3)];
                f32x4 a = (f32x4){0.f, 0.f, 0.f, 0.f};
                a = __builtin_amdgcn_mfma_f32_16x16x32_bf16(qf0, k0, a, 0, 0, 0);
                a = __builtin_amdgcn_mfma_f32_16x16x32_bf16(qf1, k1, a, 0, 0, 0);
                s[ct] = a;
            }

            // ---- causal mask (only chunks crossing the diagonal) ----
            if (s0 + 63 > t_first) {
                #pragma unroll
                for (int ct = 0; ct < 4; ++ct)
                    #pragma unroll
                    for (int r = 0; r < 4; ++r)
                        if (s0 + ct * 16 + lr > t_first + lg * 4 + r) s[ct][r] = -INFINITY;
            }

            // ---- online softmax (defer-max, log2 domain) ----
            float pm[4];
            #pragma unroll
            for (int r = 0; r < 4; ++r)
                pm[r] = fmaxf(fmaxf(s[0][r], s[1][r]), fmaxf(s[2][r], s[3][r]));
            bool near = true;
            #pragma unroll
            for (int r = 0; r < 4; ++r) near = near && (pm[r] - m[r] <= 8.0f);
            if (!__all(near)) {
                float tmax[4];
                #pragma unroll
                for (int r = 0; r < 4; ++r) tmax[r] = pm[r];
                #pragma unroll
                for (int off = 1; off < 16; off <<= 1)
                    #pragma unroll
                    for (int r = 0; r < 4; ++r)
                        tmax[r] = fmaxf(tmax[r], __shfl_xor(tmax[r], off));
                #pragma unroll
                for (int r = 0; r < 4; ++r) {
                    const float mn = fmaxf(m[r], tmax[r]);
                    const float f = exp2f(m[r] - mn);
                    m[r] = mn; L[r] *= f;
                    oacc[0][r] *= f; oacc[1][r] *= f;
                    oacc[2][r] *= f; oacc[3][r] *= f;
                }
            }
            float ps[4] = {0.f, 0.f, 0.f, 0.f};
            unsigned short pb[4][4];
            #pragma unroll
            for (int ct = 0; ct < 4; ++ct)
                #pragma unroll
                for (int r = 0; r < 4; ++r) {
                    const float p = exp2f(s[ct][r] - m[r]);
                    ps[r] += p;
                    pb[ct][r] = f2bf(p);
                }
            #pragma unroll
            for (int r = 0; r < 4; ++r) L[r] += ps[r];

            // ---- P roundtrip (per-wave LDS) ----
            #pragma unroll
            for (int ct = 0; ct < 4; ++ct)
                #pragma unroll
                for (int r = 0; r < 4; ++r)
                    P_lds[w][lg * 4 + r][ct * 16 + lr] = pb[ct][r];
            asm volatile("s_waitcnt lgkmcnt(0)" ::: "memory");
            const bf16x8 pf0 = *(const bf16x8*)&P_lds[w][lr][(lg << 3)];
            const bf16x8 pf1 = *(const bf16x8*)&P_lds[w][lr][32 + (lg << 3)];

            // ---- PV from swizzled V LDS (this wave's key-half h) ----
            #pragma unroll
            for (int dt = 0; dt < 4; ++dt) {
                const int rr = dt * 16 + lr;
                const bf16x8 v0 = *(const bf16x8*)&sh.kv.V[curb][h][rr][((lg ^ (rr & 7)) << 3)];
                const bf16x8 v1 = *(const bf16x8*)&sh.kv.V[curb][h][rr][(((lg + 4) ^ (rr & 7)) << 3)];
                oacc[dt] = __builtin_amdgcn_mfma_f32_16x16x32_bf16(pf0, v0, oacc[dt], 0, 0, 0);
                oacc[dt] = __builtin_amdgcn_mfma_f32_16x16x32_bf16(pf1, v1, oacc[dt], 0, 0, 0);
            }
        }

        if (i2 + 1 < nkb2) STAGE_WRITE(curb ^ 1); // after compute (waits vmcnt)
        __syncthreads();                           // one barrier per chunk
    }

    // ---- L reduce across lane groups ----
    #pragma unroll
    for (int off = 1; off < 16; off <<= 1)
        #pragma unroll
        for (int r = 0; r < 4; ++r) L[r] += __shfl_xor(L[r], off);

    // ---- 2-way flash-merge per tile (union reuses kv LDS; loop barrier done)
    #pragma unroll
    for (int dt = 0; dt < 4; ++dt)
        #pragma unroll
        for (int r = 0; r < 4; ++r)
            sh.mg.Op[w][(lg << 2) + r][dt * 16 + lr] = oacc[dt][r];
    if (lr == 0) {
        #pragma unroll
        for (int r = 0; r < 4; ++r) {
            sh.mg.mp[w][(lg << 2) + r] = m[r];
            sh.mg.Lp[w][(lg << 2) + r] = L[r];
        }
    }
    __syncthreads();

    const int v0 = t << 1, v1 = v0 + 1;           // this tile's two partials
    #pragma unroll
    for (int c2 = 0; c2 < 2; ++c2) {
        const int ctn = (h << 1) + c2;            // this wave's col-tiles
        #pragma unroll
        for (int r = 0; r < 4; ++r) {
            const int row = (lg << 2) + r;
            const float M = fmaxf(sh.mg.mp[v0][row], sh.mg.mp[v1][row]);
            const float f0 = exp2f(sh.mg.mp[v0][row] - M);
            const float f1 = exp2f(sh.mg.mp[v1][row] - M);
            const float Lf = f0 * sh.mg.Lp[v0][row] + f1 * sh.mg.Lp[v1][row];
            const float o  = f0 * sh.mg.Op[v0][row][(ctn << 4) + lr]
                           + f1 * sh.mg.Op[v1][row][(ctn << 4) + lr];
            O[(size_t)(q0t + row) * DK + (ctn << 4) + lr] = o / Lf;
        }
    }
#undef STAGE_LOAD
#undef STAGE_WRITE
}

extern "C" void kernel_launch(void* const* d_in, const int* in_sizes, int n_in,
                              void* d_out, int out_size, void* d_ws, size_t ws_size,
                              hipStream_t stream) {
    const float* x  = (const float*)d_in[0];
    const float* Wq = (const float*)d_in[1];
    const float* Wk = (const float*)d_in[2];
    const float* Wv = (const float*)d_in[3];
    float* O = (float*)d_out;

    unsigned short* Qb = (unsigned short*)d_ws;                 // 1 MB
    unsigned short* Kb = Qb + (size_t)BT * DK;                  // 1 MB
    unsigned short* VT = Kb + (size_t)BT * DK;                  // 1 MB (blocked)
    unsigned short* WT = VT + (size_t)BT * DK;                  // 384 KB

    wt_kernel  <<<dim3(48),  dim3(256), 0, stream>>>(Wq, Wk, Wv, WT);
    proj_kernel<<<dim3(512), dim3(256), 0, stream>>>(x, WT, Qb, Kb, VT);
    attn_kernel<<<dim3(256), dim3(256), 0, stream>>>(Qb, Kb, VT, O);
}

// Round 26
// 42.054 us; speedup vs baseline: 1.2439x; 1.2439x over previous
//
#include <hip/hip_runtime.h>
#include <math.h>

#define BT    8192
#define TSEQ  2048
#define DIN   1024
#define DK    64

typedef __attribute__((ext_vector_type(8))) short bf16x8;
typedef __attribute__((ext_vector_type(4))) short bf16x4;
typedef __attribute__((ext_vector_type(4))) float f32x4;

static __device__ inline unsigned short f2bf(float f) {
    union { float f; unsigned u; } v; v.f = f;
    unsigned r = v.u + 0x7fff + ((v.u >> 16) & 1);   // RNE
    return (unsigned short)(r >> 16);
}

static __device__ inline bf16x4 cvt4(float4 a) {
    bf16x4 r;
    r[0] = (short)f2bf(a.x); r[1] = (short)f2bf(a.y);
    r[2] = (short)f2bf(a.z); r[3] = (short)f2bf(a.w);
    return r;
}

// ---------------- WT[mat*64+n][k] = bf16(W[k][n]) : [192][1024] -------------
__global__ __launch_bounds__(256) void wt_kernel(
    const float* __restrict__ Wq, const float* __restrict__ Wk,
    const float* __restrict__ Wv, unsigned short* __restrict__ WT)
{
    __shared__ float ws[64][65];
    const int tid = threadIdx.x;
    const int mat = blockIdx.x >> 4;               // 0..2
    const int k0  = (blockIdx.x & 15) << 6;        // 0..960
    const float* W = (mat == 0) ? Wq : ((mat == 1) ? Wk : Wv);

    const int j = tid & 63;
    for (int i = tid >> 6; i < 64; i += 4)
        ws[i][j] = W[(size_t)(k0 + i) * DK + j];
    __syncthreads();

    const int n  = tid & 63;
    const int c0 = (tid >> 6) << 4;
    unsigned short* dst = WT + (size_t)(mat * 64 + n) * DIN + k0 + c0;
    #pragma unroll
    for (int c = 0; c < 16; ++c) dst[c] = f2bf(ws[c0 + c][n]);
}

// ---------------- MFMA projection: barrier-free per-wave WT pipeline (R18) --
__global__ __launch_bounds__(256, 2) void proj_kernel(
    const float* __restrict__ x, const unsigned short* __restrict__ WT,
    unsigned short* __restrict__ Qb, unsigned short* __restrict__ Kb,
    unsigned short* __restrict__ VT)
{
    __shared__ unsigned short xs[16][1032];        // 33.0 KB
    __shared__ unsigned short wtb[192][72];        // 27.6 KB, 48 rows/wave
    const int tid = threadIdx.x;
    const int m0 = blockIdx.x * 16;

    {
        const int r = tid >> 4;
        const int c = (tid & 15) << 2;
        const float* src = x + (size_t)(m0 + r) * DIN + c;
        float4 tmp[16];
        #pragma unroll
        for (int s = 0; s < 16; ++s) tmp[s] = *(const float4*)(src + s * 64);
        #pragma unroll
        for (int s = 0; s < 16; ++s) *(bf16x4*)&xs[r][c + s * 64] = cvt4(tmp[s]);
    }

    const int lane = tid & 63;
    const int w    = tid >> 6;                    // 0..3 (colgroup, 48 cols)
    const int lr = lane & 15, lg = lane >> 4;

    f32x4 acc[3];
    #pragma unroll
    for (int nt = 0; nt < 3; ++nt) acc[nt] = (f32x4){0.f, 0.f, 0.f, 0.f};

    const unsigned short* wt_w = WT + (size_t)w * 48 * DIN;   // wave's rows
    bf16x8 cur[6], nxt[6];
    #pragma unroll
    for (int i = 0; i < 6; ++i) {                 // prologue: chunk 0 loads
        const int c = lane + i * 64;              // 0..383
        const int nl = c >> 3;                    // local row 0..47
        const int sl = c & 7;                     // 16B slot
        cur[i] = *(const bf16x8*)(wt_w + (size_t)nl * DIN + (sl << 3));
    }

    __syncthreads();                              // xs ready (only barrier)

    for (int kc = 0; kc < 16; ++kc) {
        const int k0 = kc << 6;

        if (kc + 1 < 16) {
            #pragma unroll
            for (int i = 0; i < 6; ++i) {
                const int c = lane + i * 64;
                const int nl = c >> 3;
                const int sl = c & 7;
                nxt[i] = *(const bf16x8*)(wt_w + (size_t)nl * DIN
                                          + (k0 + 64) + (sl << 3));
            }
        }

        #pragma unroll
        for (int i = 0; i < 6; ++i) {
            const int c = lane + i * 64;
            const int n = w * 48 + (c >> 3);
            const int sl = c & 7;
            *(bf16x8*)&wtb[n][((sl + n) & 7) << 3] = cur[i];
        }
        asm volatile("s_waitcnt lgkmcnt(0)" ::: "memory");  // wave-local W->R

        #pragma unroll
        for (int st = 0; st < 2; ++st) {
            const bf16x8 af = *(const bf16x8*)&xs[lr][k0 + (st << 5) + (lg << 3)];
            #pragma unroll
            for (int nt = 0; nt < 3; ++nt) {
                const int n = w * 48 + nt * 16 + lr;
                const int sl = (st << 2) + lg;
                const bf16x8 bf = *(const bf16x8*)&wtb[n][((sl + n) & 7) << 3];
                acc[nt] = __builtin_amdgcn_mfma_f32_16x16x32_bf16(af, bf, acc[nt], 0, 0, 0);
            }
        }

        if (kc + 1 < 16) {
            #pragma unroll
            for (int i = 0; i < 6; ++i) cur[i] = nxt[i];
        }
    }

    const float qsc = 0.125f * 1.44269504088896340736f;  // scale * log2(e)
    #pragma unroll
    for (int nt = 0; nt < 3; ++nt) {
        const int gct = w * 3 + nt;                      // global 16-col tile
        if (gct < 8) {
            #pragma unroll
            for (int r = 0; r < 4; ++r) {
                const int row = m0 + (lg << 2) + r;
                const float vv = acc[nt][r];
                if (gct < 4) Qb[(size_t)row * DK + gct * 16 + lr] = f2bf(vv * qsc);
                else         Kb[(size_t)row * DK + (gct - 4) * 16 + lr] = f2bf(vv);
            }
        } else {
            // VT blocked: tile = (batch*32 + t/64), row d, col t%64; 8B store
            const int d = (gct - 8) * 16 + lr;
            const int t = m0 + (lg << 2);
            const int tb = t & (TSEQ - 1);
            const size_t tile = (size_t)(t >> 11) * 32 + (tb >> 6);
            ushort4 pk;
            pk.x = f2bf(acc[nt][0]); pk.y = f2bf(acc[nt][1]);
            pk.z = f2bf(acc[nt][2]); pk.w = f2bf(acc[nt][3]);
            *(ushort4*)&VT[(tile * DK + d) * 64 + (tb & 63)] = pk;
        }
    }
}

// ---------------- MFMA flash attention (R19 balance + blocked-VT reads) -----
__global__ __launch_bounds__(256, 2) void attn_kernel(
    const unsigned short* __restrict__ Qb, const unsigned short* __restrict__ Kb,
    const unsigned short* __restrict__ VT, float* __restrict__ O)
{
    __shared__ __align__(16) unsigned short P_lds[4][16][72];
    __shared__ float Opart[4][16][68];
    __shared__ float mpart[4][16];
    __shared__ float Lpart[4][16];

    const int lane = threadIdx.x & 63;
    const int w    = threadIdx.x >> 6;
    const int i    = blockIdx.x;
    const int half = i >> 8;                      // 0 = long, 1 = short
    const int k    = i & 255;
    const int batch = k & 3;
    const int j    = k >> 2;                      // 0..63
    const int qt_local = half ? j : (127 - j);
    const int q0 = (batch << 11) + (qt_local << 4);   // global row
    const int t0 = qt_local << 4;                 // within-batch row
    const int b  = batch;
    const int lr = lane & 15;
    const int lg = lane >> 4;

    const unsigned short* Qrow = Qb + (size_t)(q0 + lr) * DK + (lg << 3);
    const bf16x8 qf0 = *(const bf16x8*)(Qrow);
    const bf16x8 qf1 = *(const bf16x8*)(Qrow + 32);

    const unsigned short* Kbase = Kb + (size_t)b * TSEQ * DK;
    const unsigned short* Vbase = VT + (size_t)b * 32 * DK * 64;  // blocked tiles

    f32x4 oacc[4];
    #pragma unroll
    for (int dt = 0; dt < 4; ++dt) oacc[dt] = (f32x4){0.f, 0.f, 0.f, 0.f};
    float m[4] = {-INFINITY, -INFINITY, -INFINITY, -INFINITY};
    float L[4] = {0.f, 0.f, 0.f, 0.f};

    const int nkb = (t0 >> 6) + 1;                // 64-key blocks, within batch

    bf16x8 kf0[4], kf1[4];
    if (w < nkb) {
        const int s0 = w << 6;
        #pragma unroll
        for (int ct = 0; ct < 4; ++ct) {
            const unsigned short* Krow =
                Kbase + (size_t)(s0 + ct * 16 + lr) * DK + (lg << 3);
            kf0[ct] = *(const bf16x8*)(Krow);
            kf1[ct] = *(const bf16x8*)(Krow + 32);
        }
    }

    for (int kb = w; kb < nkb; kb += 4) {
        const int s0 = kb << 6;

        f32x4 s[4];
        #pragma unroll
        for (int ct = 0; ct < 4; ++ct) {
            f32x4 a = (f32x4){0.f, 0.f, 0.f, 0.f};
            a = __builtin_amdgcn_mfma_f32_16x16x32_bf16(qf0, kf0[ct], a, 0, 0, 0);
            a = __builtin_amdgcn_mfma_f32_16x16x32_bf16(qf1, kf1[ct], a, 0, 0, 0);
            s[ct] = a;
        }

        // ---- V loads from 8-KB-contiguous blocked tile ----
        bf16x8 vf0[4], vf1[4];
        {
            const unsigned short* Vtile = Vbase + (size_t)kb * DK * 64;
            #pragma unroll
            for (int dt = 0; dt < 4; ++dt) {
                const unsigned short* Vrow = Vtile + (dt * 16 + lr) * 64 + (lg << 3);
                vf0[dt] = *(const bf16x8*)(Vrow);
                vf1[dt] = *(const bf16x8*)(Vrow + 32);
            }
        }

        bf16x8 nk0[4], nk1[4];
        if (kb + 4 < nkb) {
            const int sn = (kb + 4) << 6;
            #pragma unroll
            for (int ct = 0; ct < 4; ++ct) {
                const unsigned short* Krow =
                    Kbase + (size_t)(sn + ct * 16 + lr) * DK + (lg << 3);
                nk0[ct] = *(const bf16x8*)(Krow);
                nk1[ct] = *(const bf16x8*)(Krow + 32);
            }
        }

        if (kb == nkb - 1) {
            #pragma unroll
            for (int ct = 0; ct < 4; ++ct)
                #pragma unroll
                for (int r = 0; r < 4; ++r)
                    if (s0 + ct * 16 + lr > t0 + lg * 4 + r) s[ct][r] = -INFINITY;
        }

        float pm[4];
        #pragma unroll
        for (int r = 0; r < 4; ++r)
            pm[r] = fmaxf(fmaxf(s[0][r], s[1][r]), fmaxf(s[2][r], s[3][r]));

        bool near = true;
        #pragma unroll
        for (int r = 0; r < 4; ++r)
            near = near && (pm[r] - m[r] <= 8.0f);

        if (!__all(near)) {
            float tmax[4];
            #pragma unroll
            for (int r = 0; r < 4; ++r) tmax[r] = pm[r];
            #pragma unroll
            for (int off = 1; off < 16; off <<= 1)
                #pragma unroll
                for (int r = 0; r < 4; ++r)
                    tmax[r] = fmaxf(tmax[r], __shfl_xor(tmax[r], off));

            float f[4];
            #pragma unroll
            for (int r = 0; r < 4; ++r) {
                const float mn = fmaxf(m[r], tmax[r]);
                f[r] = exp2f(m[r] - mn);
                m[r] = mn;
            }
            #pragma unroll
            for (int r = 0; r < 4; ++r) L[r] *= f[r];
            #pragma unroll
            for (int r = 0; r < 4; ++r) {
                oacc[0][r] *= f[r]; oacc[1][r] *= f[r];
                oacc[2][r] *= f[r]; oacc[3][r] *= f[r];
            }
        }

        float ps[4] = {0.f, 0.f, 0.f, 0.f};
        unsigned short pb[4][4];
        #pragma unroll
        for (int ct = 0; ct < 4; ++ct)
            #pragma unroll
            for (int r = 0; r < 4; ++r) {
                const float p = exp2f(s[ct][r] - m[r]);
                ps[r] += p;
                pb[ct][r] = f2bf(p);
            }
        #pragma unroll
        for (int r = 0; r < 4; ++r) L[r] += ps[r];

        #pragma unroll
        for (int ct = 0; ct < 4; ++ct)
            #pragma unroll
            for (int r = 0; r < 4; ++r)
                P_lds[w][lg * 4 + r][ct * 16 + lr] = pb[ct][r];
        asm volatile("s_waitcnt lgkmcnt(0)" ::: "memory");
        const bf16x8 pf0 = *(const bf16x8*)&P_lds[w][lr][(lg << 3)];
        const bf16x8 pf1 = *(const bf16x8*)&P_lds[w][lr][32 + (lg << 3)];

        #pragma unroll
        for (int dt = 0; dt < 4; ++dt) {
            oacc[dt] = __builtin_amdgcn_mfma_f32_16x16x32_bf16(pf0, vf0[dt], oacc[dt], 0, 0, 0);
            oacc[dt] = __builtin_amdgcn_mfma_f32_16x16x32_bf16(pf1, vf1[dt], oacc[dt], 0, 0, 0);
        }

        #pragma unroll
        for (int ct = 0; ct < 4; ++ct) { kf0[ct] = nk0[ct]; kf1[ct] = nk1[ct]; }
    }

    #pragma unroll
    for (int off = 1; off < 16; off <<= 1)
        #pragma unroll
        for (int r = 0; r < 4; ++r) L[r] += __shfl_xor(L[r], off);

    #pragma unroll
    for (int dt = 0; dt < 4; ++dt)
        #pragma unroll
        for (int r = 0; r < 4; ++r)
            Opart[w][(lg << 2) + r][dt * 16 + lr] = oacc[dt][r];
    if (lr == 0) {
        #pragma unroll
        for (int r = 0; r < 4; ++r) {
            mpart[w][(lg << 2) + r] = m[r];
            Lpart[w][(lg << 2) + r] = L[r];
        }
    }
    __syncthreads();

    #pragma unroll
    for (int r = 0; r < 4; ++r) {
        const int row = (lg << 2) + r;
        const float M = fmaxf(fmaxf(mpart[0][row], mpart[1][row]),
                              fmaxf(mpart[2][row], mpart[3][row]));
        float Lf = 0.f, o = 0.f;
        #pragma unroll
        for (int v = 0; v < 4; ++v) {
            const float fv = exp2f(mpart[v][row] - M);
            Lf += fv * Lpart[v][row];
            o  += fv * Opart[v][row][(w << 4) + lr];
        }
        O[(size_t)(q0 + row) * DK + (w << 4) + lr] = o / Lf;
    }
}

extern "C" void kernel_launch(void* const* d_in, const int* in_sizes, int n_in,
                              void* d_out, int out_size, void* d_ws, size_t ws_size,
                              hipStream_t stream) {
    const float* x  = (const float*)d_in[0];
    const float* Wq = (const float*)d_in[1];
    const float* Wk = (const float*)d_in[2];
    const float* Wv = (const float*)d_in[3];
    float* O = (float*)d_out;

    unsigned short* Qb = (unsigned short*)d_ws;                 // 1 MB
    unsigned short* Kb = Qb + (size_t)BT * DK;                  // 1 MB
    unsigned short* VT = Kb + (size_t)BT * DK;                  // 1 MB (blocked)
    unsigned short* WT = VT + (size_t)BT * DK;                  // 384 KB

    wt_kernel  <<<dim3(48),  dim3(256), 0, stream>>>(Wq, Wk, Wv, WT);
    proj_kernel<<<dim3(512), dim3(256), 0, stream>>>(x, WT, Qb, Kb, VT);
    attn_kernel<<<dim3(512), dim3(256), 0, stream>>>(Qb, Kb, VT, O);
}